// Round 1
// baseline (1548.573 us; speedup 1.0000x reference)
//
#include <hip/hip_runtime.h>

// CapsNet dynamic routing, fused per-iteration.
// Shapes: x[64][2048][16], kernel[2048][32][16][32], out V[64][32][32], all fp32.
//
// Per routing iteration one caps_pass kernel recomputes U[b,n,j,d] on the fly
// and produces per-block S partials; reduce_squash sums partials and applies
// squash to give V. Blog lives in ws ([b][n][j], 16 MB). No atomics, no memsets.

#define NIN   2048
#define DIN   16
#define NOUT  32
#define DOUT  32
#define NTILE 16            // n per block
#define NB    (NIN/NTILE)   // 128 n-tiles
#define BLK   512           // 16 tb * 32 j
#define TBS   16

// ws layout (floats):
//   Blog  : 64*2048*32            = 4194304
//   Spart : 2*NB * 32*32*32       = 8388608   (per-block partial S, [bh*NB+nt][bl][j][d])
//   V     : 64*32*32              = 65536

__device__ __forceinline__ float grp_max32(float v) {
#pragma unroll
  for (int m = 16; m >= 1; m >>= 1) v = fmaxf(v, __shfl_xor(v, m, 64));
  return v;
}
__device__ __forceinline__ float grp_sum32(float v) {
#pragma unroll
  for (int m = 16; m >= 1; m >>= 1) v += __shfl_xor(v, m, 64);
  return v;
}

// MODE 0: C = 1/32 uniform (iteration 0, softmax of zeros)
// MODE 1: dot = U.V0; Blog = dot (write); C = softmax_j(dot)
// MODE 2: l = Blog + U.V1 (read);        C = softmax_j(l)
template<int MODE>
__global__ __launch_bounds__(BLK, 2) void caps_pass(
    const float* __restrict__ x, const float* __restrict__ Kr,
    const float* __restrict__ Vin, float* __restrict__ Blog,
    float* __restrict__ Spart)
{
  const int tid = threadIdx.x;
  const int j   = tid & 31;          // output capsule
  const int tb  = tid >> 5;          // 0..15
  const int bh  = blockIdx.y;        // batch half
  const int nt  = blockIdx.x;        // n-tile
  const int n0  = nt * NTILE;
  const int b0  = bh * 32 + tb;
  const int b1  = b0 + TBS;

  __shared__ float xs[32][NTILE * DIN];   // 32 KB: x for this half's 32 b, 16 n

  for (int i = tid; i < 32 * 64; i += BLK) {
    const int bl = i >> 6, q = i & 63;
    const float4 v = *(const float4*)(x + ((size_t)(bh * 32 + bl) * NIN + n0) * DIN + q * 4);
    *(float4*)&xs[bl][q * 4] = v;
  }
  __syncthreads();

  float s0[DOUT], s1[DOUT];
#pragma unroll
  for (int d = 0; d < DOUT; ++d) { s0[d] = 0.f; s1[d] = 0.f; }

#pragma unroll 1
  for (int nn = 0; nn < NTILE; ++nn) {
    const int n = n0 + nn;
    // kernel[n][j][k][d]: 512 contiguous floats per (n,j)
    const float4* Kp = (const float4*)(Kr + ((size_t)n * NOUT + j) * (DIN * DOUT));

    float u0[DOUT], u1[DOUT];
#pragma unroll
    for (int d = 0; d < DOUT; ++d) { u0[d] = 0.f; u1[d] = 0.f; }

#pragma unroll
    for (int k = 0; k < DIN; ++k) {
      const float xa = xs[tb][nn * DIN + k];
      const float xb = xs[tb + TBS][nn * DIN + k];
#pragma unroll
      for (int q = 0; q < 8; ++q) {
        const float4 kv = Kp[k * 8 + q];
        u0[q*4+0] = fmaf(xa, kv.x, u0[q*4+0]);
        u0[q*4+1] = fmaf(xa, kv.y, u0[q*4+1]);
        u0[q*4+2] = fmaf(xa, kv.z, u0[q*4+2]);
        u0[q*4+3] = fmaf(xa, kv.w, u0[q*4+3]);
        u1[q*4+0] = fmaf(xb, kv.x, u1[q*4+0]);
        u1[q*4+1] = fmaf(xb, kv.y, u1[q*4+1]);
        u1[q*4+2] = fmaf(xb, kv.z, u1[q*4+2]);
        u1[q*4+3] = fmaf(xb, kv.w, u1[q*4+3]);
      }
    }

    float C0, C1;
    if (MODE == 0) {
      C0 = 0.03125f; C1 = 0.03125f;
    } else {
      const float4* Vp0 = (const float4*)(Vin + ((size_t)b0 * NOUT + j) * DOUT);
      const float4* Vp1 = (const float4*)(Vin + ((size_t)b1 * NOUT + j) * DOUT);
      float dot0 = 0.f, dot1 = 0.f;
#pragma unroll
      for (int q = 0; q < 8; ++q) {
        const float4 va = Vp0[q];
        const float4 vb = Vp1[q];
        dot0 += u0[q*4+0]*va.x + u0[q*4+1]*va.y + u0[q*4+2]*va.z + u0[q*4+3]*va.w;
        dot1 += u1[q*4+0]*vb.x + u1[q*4+1]*vb.y + u1[q*4+2]*vb.z + u1[q*4+3]*vb.w;
      }
      const size_t bi0 = ((size_t)b0 * NIN + n) * NOUT + j;
      const size_t bi1 = ((size_t)b1 * NIN + n) * NOUT + j;
      float l0, l1;
      if (MODE == 1) {
        l0 = dot0; l1 = dot1;
        Blog[bi0] = l0;
        Blog[bi1] = l1;
      } else {
        l0 = Blog[bi0] + dot0;
        l1 = Blog[bi1] + dot1;
      }
      // softmax over j (lanes 0..31 of each 32-lane group)
      const float m0 = grp_max32(l0);
      const float m1 = grp_max32(l1);
      const float e0 = __expf(l0 - m0);
      const float e1 = __expf(l1 - m1);
      C0 = e0 / grp_sum32(e0);
      C1 = e1 / grp_sum32(e1);
    }

#pragma unroll
    for (int d = 0; d < DOUT; ++d) {
      s0[d] = fmaf(C0, u0[d], s0[d]);
      s1[d] = fmaf(C1, u1[d], s1[d]);
    }
  }

  // write per-block partial S: [bh*NB+nt][bl][j][d]
  float* P = Spart + (size_t)(bh * NB + nt) * (32 * NOUT * DOUT);
#pragma unroll
  for (int q = 0; q < 8; ++q) {
    *(float4*)&P[((size_t)tb * NOUT + j) * DOUT + q * 4] =
        make_float4(s0[q*4], s0[q*4+1], s0[q*4+2], s0[q*4+3]);
    *(float4*)&P[((size_t)(tb + TBS) * NOUT + j) * DOUT + q * 4] =
        make_float4(s1[q*4], s1[q*4+1], s1[q*4+2], s1[q*4+3]);
  }
}

// Sum the NB partials per batch-half, then squash along d (in-wave, d = lane bits 0..4).
__global__ __launch_bounds__(256) void reduce_squash(
    const float* __restrict__ Spart, float* __restrict__ Vout)
{
  const int idx = blockIdx.x * 256 + threadIdx.x;   // 0..65535 = [b][j][d]
  const int d  = idx & 31;
  const int j  = (idx >> 5) & 31;
  const int b  = idx >> 10;
  const int bh = b >> 5, bl = b & 31;
  const float* p = Spart + (size_t)bh * NB * (32 * NOUT * DOUT)
                   + ((size_t)bl * NOUT + j) * DOUT + d;
  float s = 0.f;
#pragma unroll 8
  for (int t = 0; t < NB; ++t) s += p[(size_t)t * (32 * NOUT * DOUT)];
  float sq = s * s;
#pragma unroll
  for (int m = 16; m >= 1; m >>= 1) sq += __shfl_xor(sq, m, 64);
  Vout[idx] = s * (sq / (1.0f + sq)) * rsqrtf(sq + 1e-8f);
}

extern "C" void kernel_launch(void* const* d_in, const int* in_sizes, int n_in,
                              void* d_out, int out_size, void* d_ws, size_t ws_size,
                              hipStream_t stream) {
  const float* x  = (const float*)d_in[0];
  const float* Kr = (const float*)d_in[1];
  float* ws    = (float*)d_ws;
  float* Blog  = ws;
  float* Spart = ws + 4194304;
  float* V     = ws + 4194304 + 8388608;
  float* out   = (float*)d_out;

  const dim3 g(NB, 2), blk(BLK);
  // iter 0 (uniform C) -> V0
  caps_pass<0><<<g, blk, 0, stream>>>(x, Kr, nullptr, Blog, Spart);
  reduce_squash<<<256, 256, 0, stream>>>(Spart, V);
  // iter 1: Blog = U.V0, C = softmax -> V1
  caps_pass<1><<<g, blk, 0, stream>>>(x, Kr, V, Blog, Spart);
  reduce_squash<<<256, 256, 0, stream>>>(Spart, V);
  // iter 2: C = softmax(Blog + U.V1) -> V2 = output
  caps_pass<2><<<g, blk, 0, stream>>>(x, Kr, V, Blog, Spart);
  reduce_squash<<<256, 256, 0, stream>>>(Spart, out);
}

// Round 3
// 397.361 us; speedup vs baseline: 3.8971x; 3.8971x over previous
//
#include <hip/hip_runtime.h>

// CapsNet dynamic routing via bf16 MFMA (v_mfma_f32_32x32x16_bf16).
// Shapes: x[64][2048][16], kernel[2048][32][16][32], out V[64][32][32], fp32 in/out.
//
// One-time per launch: repack kernel -> bf16 fragment-order Ktf[n][d][lane][8],
// x -> bf16 xtf[bh][n][lane][8]. Then 3 routing passes: per n, U[32b x 32j] for
// each d comes from ONE MFMA; dot/softmax/S-accum fused around it.

#define NIN   2048
#define DIN   16
#define NOUT  32
#define DOUT  32
#define NTILE 16
#define NB    (NIN/NTILE)   // 128

typedef __attribute__((ext_vector_type(8)))  short s16x8;
typedef __attribute__((ext_vector_type(16))) float f32x16;

// ws float offsets
#define WS_BLOG  0                         // 64*2048*32          = 4194304 f
#define WS_SPART 4194304                   // 256 * 32*32*32      = 8388608 f
#define WS_V     (WS_SPART + 8388608)      // 64*32*32            = 65536 f
#define WS_KTF   (WS_V + 65536)            // 2048*32*64*8 bf16   = 16777216 f-equiv
#define WS_XTF   (WS_KTF + 16777216)       // 2*2048*64*8 bf16    = 1048576 f-equiv
// total = 30,474,240 floats ~= 122 MB

__device__ __forceinline__ unsigned short f2bf(float f) {
  unsigned u = __float_as_uint(f);
  u = (u + 0x7fffu + ((u >> 16) & 1u)) >> 16;
  return (unsigned short)u;
}

// Repack kernel[n][j][k][d] fp32 -> Ktf[n][d][lane][i] bf16 via LDS transpose.
// B-fragment convention: col j = lane&31, k = (lane>>5)*8 + i  (same as A's).
__global__ __launch_bounds__(256) void conv_k(const float* __restrict__ Kr,
                                              unsigned short* __restrict__ Ktf) {
  const int n = blockIdx.x;
  const int t = threadIdx.x;
  __shared__ float kl[16384];               // 64 KB: K[n] swizzled (d-quad ^ j&7)
  const float* src = Kr + (size_t)n * 16384;
#pragma unroll
  for (int c = 0; c < 16; ++c) {
    const int idx = (c * 256 + t) * 4;      // linear dword idx = j*512 + k*32 + d
    const int jj  = idx >> 9;
    const int sidx = (idx & ~28) | (((((idx >> 2) & 7) ^ (jj & 7))) << 2);
    *(float4*)&kl[sidx] = *(const float4*)(src + idx);
  }
  __syncthreads();
  unsigned short* dst = Ktf + (size_t)n * 16384;
#pragma unroll
  for (int c = 0; c < 8; ++c) {
    const int chunk = c * 256 + t;          // (d, lane)
    const int d = chunk >> 6, lane = chunk & 63;
    const int j = lane & 31, khi = lane >> 5;
    const int dsw = ((((d >> 2) ^ (j & 7)) << 2)) | (d & 3);
    unsigned short u8[8];
#pragma unroll
    for (int i = 0; i < 8; ++i)
      u8[i] = f2bf(kl[j * 512 + (khi * 8 + i) * 32 + dsw]);
    uint4 o;
    o.x = u8[0] | ((unsigned)u8[1] << 16);
    o.y = u8[2] | ((unsigned)u8[3] << 16);
    o.z = u8[4] | ((unsigned)u8[5] << 16);
    o.w = u8[6] | ((unsigned)u8[7] << 16);
    *(uint4*)(dst + (size_t)chunk * 8) = o;
  }
}

// x[b][n][k] fp32 -> xtf[bh][n][lane][i] bf16; A-frag: row b = lane&31, k = (lane>>5)*8+i
__global__ __launch_bounds__(256) void conv_x(const float* __restrict__ x,
                                              unsigned short* __restrict__ xtf) {
  const int g = blockIdx.x * 256 + threadIdx.x;   // 262144 chunks
  const int bh = g >> 17, rem = g & 131071;
  const int n = rem >> 6, lane = rem & 63;
  const int b = bh * 32 + (lane & 31), khi = lane >> 5;
  const float* src = x + ((size_t)b * NIN + n) * DIN + khi * 8;
  unsigned short u8[8];
#pragma unroll
  for (int i = 0; i < 8; ++i) u8[i] = f2bf(src[i]);
  uint4 o;
  o.x = u8[0] | ((unsigned)u8[1] << 16);
  o.y = u8[2] | ((unsigned)u8[3] << 16);
  o.z = u8[4] | ((unsigned)u8[5] << 16);
  o.w = u8[6] | ((unsigned)u8[7] << 16);
  *(uint4*)(xtf + (size_t)g * 8) = o;
}

// MODE 0: C = 1/32 uniform. MODE 1: Blog = U.V (write), C = softmax.
// MODE 2: l = Blog + U.V (read), C = softmax.
// Block: 512 thr = 8 waves; wave w owns d in [4w, 4w+4). Grid (128 nt, 2 bh).
// C/D layout (verified): col = lane&31 (=j), row b = (r&3) + 4*(lane>>5) + 8*(r>>2).
template<int MODE>
__global__ __launch_bounds__(512, 2) void caps_mfma(
    const unsigned short* __restrict__ Ktf, const unsigned short* __restrict__ xtf,
    const float* __restrict__ Vin, float* __restrict__ Blog,
    float* __restrict__ Spart)
{
  const int tid = threadIdx.x;
  const int w = tid >> 6, lane = tid & 63;
  const int j = lane & 31, hi = lane >> 5;
  const int nt = blockIdx.x, bh = blockIdx.y;
  const int n0 = nt * NTILE;

  __shared__ float Ds[8][32][32];   // per-wave partial dots [w][b][j]
  __shared__ float Cs[32][32];      // softmax coefficients [b][j]

  float sacc[16][4];
#pragma unroll
  for (int r = 0; r < 16; ++r)
#pragma unroll
    for (int dd = 0; dd < 4; ++dd) sacc[r][dd] = 0.f;

  float vreg[16][4];                // V[b(r,hi)][j][4w+dd], loaded once
  if (MODE != 0) {
#pragma unroll
    for (int r = 0; r < 16; ++r) {
      const int b = (r & 3) + 4 * hi + 8 * (r >> 2);
      const float4 v4 = *(const float4*)(Vin + (((size_t)(bh * 32 + b) * 32 + j) * 32 + w * 4));
      vreg[r][0] = v4.x; vreg[r][1] = v4.y; vreg[r][2] = v4.z; vreg[r][3] = v4.w;
    }
  }

  const int rb = tid >> 5;          // reduce-phase b0 (0..15); b1 = rb+16
  const int rj = tid & 31;

  for (int nn = 0; nn < NTILE; ++nn) {
    const int n = n0 + nn;
    const s16x8 a = *(const s16x8*)(xtf + (((size_t)bh * NIN + n) * 64 + lane) * 8);
    f32x16 u[4];
#pragma unroll
    for (int dd = 0; dd < 4; ++dd) {
      const int d = w * 4 + dd;
      const s16x8 bfrag = *(const s16x8*)(Ktf + (((size_t)n * 32 + d) * 64 + lane) * 8);
      f32x16 z;
#pragma unroll
      for (int q = 0; q < 16; ++q) z[q] = 0.f;
      u[dd] = __builtin_amdgcn_mfma_f32_32x32x16_bf16(a, bfrag, z, 0, 0, 0);
    }

    if (MODE == 0) {
#pragma unroll
      for (int r = 0; r < 16; ++r)
#pragma unroll
        for (int dd = 0; dd < 4; ++dd)
          sacc[r][dd] += 0.03125f * u[dd][r];
    } else {
      // per-wave partial dot over its 4 d's -> Ds[w][b][j]  (bank = j, conflict-free)
#pragma unroll
      for (int r = 0; r < 16; ++r) {
        const float pd = u[0][r] * vreg[r][0] + u[1][r] * vreg[r][1]
                       + u[2][r] * vreg[r][2] + u[3][r] * vreg[r][3];
        const int b = (r & 3) + 4 * hi + 8 * (r >> 2);
        Ds[w][b][j] = pd;
      }
      __syncthreads();
      // full dot = sum over 8 waves; Blog update; in-wave softmax over j
      float l0 = 0.f, l1 = 0.f;
#pragma unroll
      for (int ww = 0; ww < 8; ++ww) { l0 += Ds[ww][rb][rj]; l1 += Ds[ww][rb + 16][rj]; }
      const size_t bi0 = ((size_t)(bh * 32 + rb) * NIN + n) * 32 + rj;
      const size_t bi1 = ((size_t)(bh * 32 + rb + 16) * NIN + n) * 32 + rj;
      if (MODE == 1) { Blog[bi0] = l0; Blog[bi1] = l1; }
      else           { l0 += Blog[bi0]; l1 += Blog[bi1]; }
      float m0 = l0, m1 = l1;
#pragma unroll
      for (int mm = 16; mm >= 1; mm >>= 1) {
        m0 = fmaxf(m0, __shfl_xor(m0, mm, 64));
        m1 = fmaxf(m1, __shfl_xor(m1, mm, 64));
      }
      const float e0 = __expf(l0 - m0), e1 = __expf(l1 - m1);
      float s0 = e0, s1 = e1;
#pragma unroll
      for (int mm = 16; mm >= 1; mm >>= 1) {
        s0 += __shfl_xor(s0, mm, 64);
        s1 += __shfl_xor(s1, mm, 64);
      }
      Cs[rb][rj]      = e0 / s0;
      Cs[rb + 16][rj] = e1 / s1;
      __syncthreads();
      // S += C * U   (Cs read: bank = j, conflict-free)
#pragma unroll
      for (int r = 0; r < 16; ++r) {
        const int b = (r & 3) + 4 * hi + 8 * (r >> 2);
        const float c = Cs[b][j];
#pragma unroll
        for (int dd = 0; dd < 4; ++dd) sacc[r][dd] += c * u[dd][r];
      }
    }
  }

  float* Sp = Spart + (size_t)(bh * NB + nt) * 32768;
#pragma unroll
  for (int r = 0; r < 16; ++r) {
    const int b = (r & 3) + 4 * hi + 8 * (r >> 2);
    *(float4*)(Sp + ((size_t)b * 32 + j) * 32 + w * 4) =
        make_float4(sacc[r][0], sacc[r][1], sacc[r][2], sacc[r][3]);
  }
}

// Sum the NB partials per batch-half, then squash along d (in-wave, d = lane bits 0..4).
__global__ __launch_bounds__(256) void reduce_squash(
    const float* __restrict__ Spart, float* __restrict__ Vout)
{
  const int idx = blockIdx.x * 256 + threadIdx.x;   // [b][j][d]
  const int d  = idx & 31;
  const int jj = (idx >> 5) & 31;
  const int b  = idx >> 10;
  const int bh = b >> 5, bl = b & 31;
  const float* p = Spart + (size_t)bh * NB * 32768 + ((size_t)bl * NOUT + jj) * DOUT + d;
  float s = 0.f;
#pragma unroll 8
  for (int t = 0; t < NB; ++t) s += p[(size_t)t * 32768];
  float sq = s * s;
#pragma unroll
  for (int m = 16; m >= 1; m >>= 1) sq += __shfl_xor(sq, m, 64);
  Vout[idx] = s * (sq / (1.0f + sq)) * rsqrtf(sq + 1e-8f);
}

extern "C" void kernel_launch(void* const* d_in, const int* in_sizes, int n_in,
                              void* d_out, int out_size, void* d_ws, size_t ws_size,
                              hipStream_t stream) {
  const float* x  = (const float*)d_in[0];
  const float* Kr = (const float*)d_in[1];
  float* ws = (float*)d_ws;
  float* Blog  = ws + WS_BLOG;
  float* Spart = ws + WS_SPART;
  float* V     = ws + WS_V;
  unsigned short* Ktf = (unsigned short*)(ws + WS_KTF);
  unsigned short* xtf = (unsigned short*)(ws + WS_XTF);
  float* out = (float*)d_out;

  conv_k<<<NIN, 256, 0, stream>>>(Kr, Ktf);
  conv_x<<<1024, 256, 0, stream>>>(x, xtf);

  const dim3 g(NB, 2), blk(512);
  caps_mfma<0><<<g, blk, 0, stream>>>(Ktf, xtf, nullptr, Blog, Spart);
  reduce_squash<<<256, 256, 0, stream>>>(Spart, V);
  caps_mfma<1><<<g, blk, 0, stream>>>(Ktf, xtf, V, Blog, Spart);
  reduce_squash<<<256, 256, 0, stream>>>(Spart, V);
  caps_mfma<2><<<g, blk, 0, stream>>>(Ktf, xtf, V, Blog, Spart);
  reduce_squash<<<256, 256, 0, stream>>>(Spart, out);
}